// Round 4
// baseline (503.675 us; speedup 1.0000x reference)
//
#include <hip/hip_runtime.h>

// RNN_73813307949430: 4x LSTM(H=50,T=10,F=5) + Dense(50) + Dense(1,sigmoid), B=131072.
// Round 7: MTILE 32->16 (one M-tile). LDS 40960->20480 B so LDS allows 8 blocks/CU;
// register live-set shrinks (acc 32->16 etc, ~110 unified regs -> 128-granule) so the
// HW schedules 4 blocks/CU = 16 waves/CU (50%) vs 12 before. R6 showed the kernel is
// issue-saturated when running (VALU 68 + MFMA 30) with 32% dependency-shadow idle;
// only more resident independent blocks fill that. launch_bounds stays (256,3) — R5
// proved forcing 4 waves/EU makes the allocator spill (96MB scratch).
//
// LDS buf per t (1024 u16 = 2 KB): chunk(kk,quad) at u16 offset (kk*4+quad)*128+rr*8
// holds h[row=rr][unit=kk*32+quad*8+j]. MFMA A-frag: lane(np,quad) reads 16B at
// t*1024 + kk*512 + quad*128 + np*8 -> consecutive per lane = conflict-free.
// Weights Wpp: k 0..63 = X/h^{l-1}, k 64..127 = recurrent, prescaled by +-log2e.
// 1 barrier/step: X comes from regs (prefetched from buf[t+1]/buf[0] last step),
// reads touch only buf[t-1] and buf[t+1], disjoint from gate writes to buf[t].

typedef __attribute__((ext_vector_type(8))) short short8;
typedef __attribute__((ext_vector_type(4))) float floatx4;
typedef __attribute__((ext_vector_type(2))) float float2v;
typedef unsigned short u16;
typedef unsigned int u32;

constexpr int H_ = 50, T_ = 10, F_ = 5;
constexpr int MTILE = 16;   // batch rows per block
constexpr int BLKT = 256;   // 4 waves
constexpr float LOG2E = 1.4426950408889634f;

__device__ __forceinline__ float rcp_(float x) { return __builtin_amdgcn_rcpf(x); }
__device__ __forceinline__ float exp2_(float x) { return __builtin_amdgcn_exp2f(x); }
__device__ __forceinline__ float sig_nat(float x) {
  return rcp_(1.0f + exp2_(-LOG2E * x));
}

__device__ __forceinline__ u16 f2bf(float f) {
  union { float f; unsigned u; } v; v.f = f;
  unsigned r = v.u + 0x7FFFu + ((v.u >> 16) & 1u);  // RNE
  return (u16)(r >> 16);
}
__device__ __forceinline__ float bf2f(u16 s) {
  union { unsigned u; float f; } v; v.u = ((unsigned)s) << 16;
  return v.f;
}
// gfx950 packed f32->bf16 RNE convert (no builtin; inline asm). lo->bits[15:0].
__device__ __forceinline__ unsigned cvt_pk_bf16(float lo, float hi) {
  unsigned r;
  asm("v_cvt_pk_bf16_f32 %0, %1, %2" : "=v"(r) : "v"(lo), "v"(hi));
  return r;
}

// ---- prep: swizzle weights into B-fragment order with activation prescale ----
// Wpp[layer][kt][gate][wave][lane][8]; B[k=(lane>>4)*8+j][n=lane&15].
// Gates i,f,o scaled by -log2e (sig = rcp(1+exp2(z))); gate g by +2*log2e
// (tanh = 1-2*rcp(1+exp2(z))). Bias scaled identically.
__global__ void prep_kernel(
    const float* W1, const float* U1, const float* b1, const float* W2,
    const float* U2, const float* b2, const float* W3, const float* U3,
    const float* b3, const float* W4, const float* U4, const float* b4,
    const float* Wd1, const float* bd1, const float* Wd2, const float* bd2,
    u16* Wpp, float* biasP, float* vdense) {
  int idx = blockIdx.x * blockDim.x + threadIdx.x;
  const float* Wt[4] = {W1, W2, W3, W4};
  const float* Ut[4] = {U1, U2, U3, U4};
  const float* bt[4] = {b1, b2, b3, b4};
  const int fin[4] = {F_, H_, H_, H_};
  if (idx < 4 * 32768) {
    int l = idx >> 15, r = idx & 32767;
    int j = r & 7, lane = (r >> 3) & 63, w = (r >> 9) & 3, gI = (r >> 11) & 3,
        kt = r >> 13;
    int row = kt * 32 + (lane >> 4) * 8 + j;  // K position (0..127)
    int u = w * 16 + (lane & 15);             // unit (0..63)
    float val = 0.0f;
    if (u < H_) {
      if (row < 64) {
        if (row < fin[l]) val = Wt[l][row * 200 + gI * H_ + u];
      } else {
        int rr = row - 64;
        if (rr < H_) val = Ut[l][rr * 200 + gI * H_ + u];
      }
    }
    val *= (gI == 2) ? (2.0f * LOG2E) : (-LOG2E);
    Wpp[idx] = f2bf(val);
  } else if (idx < 4 * 32768 + 1024) {
    int r = idx - 4 * 32768;
    int l = r >> 8, q = r & 255, gI = q >> 6, u = q & 63;
    float val = (u < H_) ? bt[l][gI * H_ + u] : 0.0f;
    biasP[r] = val * ((gI == 2) ? (2.0f * LOG2E) : (-LOG2E));
  } else if (idx < 4 * 32768 + 1024 + 51) {
    int u = idx - (4 * 32768 + 1024);
    if (u < H_) {  // v = Wd1 @ Wd2 (Dense(50) linear -> collapse)
      float s = 0.0f;
      for (int n = 0; n < H_; ++n) s += Wd1[u * H_ + n] * Wd2[n];
      vdense[u] = s;
    } else {
      float s = bd2[0];
      for (int n = 0; n < H_; ++n) s += bd1[n] * Wd2[n];
      vdense[50] = s;
    }
  }
}

// ---- fully fused 4-layer LSTM + dense head ----
__global__ __launch_bounds__(BLKT, 3) void lstm_fused(
    const float* __restrict__ x0, const u16* __restrict__ Wpp,
    const float* __restrict__ biasP, const float* __restrict__ vdense,
    float* __restrict__ out) {
  // buf[t]: 1024 u16 (2 KB). Holds x (layer 0 input) at k=0..4, then in-place
  // h^{l-1}_t as X input, overwritten with h^l_t in the gate phase.
  __shared__ __align__(16) u16 buf[T_ * 1024];  // 20480 B

  const int tid = threadIdx.x;
  const int w = tid >> 6, lane = tid & 63;
  const int np = lane & 15, quad = lane >> 4;
  const int b0 = blockIdx.x * MTILE;
  const int u = w * 16 + np;

  // zero-fill buf once (layer-0 kt=0 MFMA reads k=5..31 slots; weights there are
  // zero, but LDS garbage could be NaN -> 0*NaN=NaN, so they must be real zeros)
  for (int i = tid; i < T_ * 512; i += BLKT) ((u32*)buf)[i] = 0;
  __syncthreads();
  // stage ALL timesteps of layer-1 input into buf[t] fragment slots (k=f, 0..4)
  for (int e = tid; e < MTILE * 50; e += BLKT) {
    int row = e / 50, q = e - row * 50;
    int t = q / 5, f = q - t * 5;
    buf[t * 1024 + row * 8 + f] = f2bf(x0[(size_t)(b0 + row) * 50 + q]);
  }
  __syncthreads();

  // A-frag read base: chunk(kk,quad,rr=np) -> kk*512 + quad*128 + np*8
  const int rbase = quad * 128 + np * 8;
  // h-write base: unit u -> kk=u>>5=w>>1, qk=((w&1)*2+(np>>3)), j=np&7; rows quad*4+2p
  const int cb0 = (w >> 1) * 512 + ((w & 1) * 2 + (np >> 3)) * 128 + quad * 32 + (np & 7);

  float2v cst[2];  // c state pairs: [p], rows quad*4+{2p,2p+1}, unit u

  // X fragments for the CURRENT step, prefetched one step ahead.
  short8 xa0, xa1;
  xa0 = *(const short8*)&buf[rbase];  // l=0,t=0 prologue: x in buf[0], kt=0 only
  xa1 = xa0;                          // unused for l=0 (defined to avoid UB)

#pragma unroll 1
  for (int l = 0; l < 4; ++l) {
    // per-layer weight fragments from L2 (prescaled), 64 VGPRs
    const u16* wp = Wpp + l * 32768;
    short8 bfr[4][4];
#pragma unroll
    for (int kt = 0; kt < 4; ++kt)
#pragma unroll
      for (int g = 0; g < 4; ++g)
        bfr[kt][g] = *(const short8*)&wp[(((kt * 4 + g) * 4 + w) * 64 + lane) * 8];
    float bv[4];
#pragma unroll
    for (int g = 0; g < 4; ++g) bv[g] = biasP[l * 256 + g * 64 + u];
    cst[0] = float2v{0.0f, 0.0f};
    cst[1] = float2v{0.0f, 0.0f};

#pragma unroll 1
    for (int t = 0; t < T_; ++t) {
      u16* bt = &buf[t * 1024];
      const u16* bp = &buf[(t == 0 ? 0 : (t - 1)) * 1024];

      floatx4 acc[4];
#pragma unroll
      for (int g = 0; g < 4; ++g) acc[g] = floatx4{bv[g], bv[g], bv[g], bv[g]};

      // X = prefetched regs (x for l=0 -> kt=0 only; h^{l-1}_t for l>0).
#pragma unroll
      for (int g = 0; g < 4; ++g)
        acc[g] = __builtin_amdgcn_mfma_f32_16x16x32_bf16(xa0, bfr[0][g], acc[g],
                                                         0, 0, 0);
      if (l > 0) {
#pragma unroll
        for (int g = 0; g < 4; ++g)
          acc[g] = __builtin_amdgcn_mfma_f32_16x16x32_bf16(xa1, bfr[1][g],
                                                           acc[g], 0, 0, 0);
      }
      if (t > 0) {  // recurrent H = h^l_{t-1} in buf[t-1]; h_{-1}=0 -> skip at t=0
        short8 h0 = *(const short8*)&bp[rbase];
        short8 h1 = *(const short8*)&bp[512 + rbase];
#pragma unroll
        for (int g = 0; g < 4; ++g) {
          acc[g] = __builtin_amdgcn_mfma_f32_16x16x32_bf16(h0, bfr[2][g], acc[g],
                                                           0, 0, 0);
          acc[g] = __builtin_amdgcn_mfma_f32_16x16x32_bf16(h1, bfr[3][g], acc[g],
                                                           0, 0, 0);
        }
      }

      // ---- prefetch next step's X frags (in flight under the gate phase) ----
      // t<9: buf[t+1] (overwritten only at step t+1, after the barrier).
      // t==9, l<3: buf[0] = h^l_0 for next layer (final since step 0).
      if (t < T_ - 1) {
        const u16* ns = &buf[(t + 1) * 1024];
        xa0 = *(const short8*)&ns[rbase];
        if (l > 0) xa1 = *(const short8*)&ns[512 + rbase];
      } else if (l < 3) {
        xa0 = *(const short8*)&buf[rbase];
        xa1 = *(const short8*)&buf[512 + rbase];
      }

      // NO pre-gate barrier: this step's LDS reads touch only buf[t-1] and
      // buf[t+1]/buf[0], all disjoint from the gate writes to buf[t]. The X-reads
      // of buf[t] happened last step, before the end-of-step barrier.

      // ---- gates: pairwise (v_pk_f32), shared reciprocals, prescaled z ----
#pragma unroll
      for (int p = 0; p < 2; ++p) {
        float2v di = {exp2_(acc[0][2 * p]), exp2_(acc[0][2 * p + 1])};
        float2v df = {exp2_(acc[1][2 * p]), exp2_(acc[1][2 * p + 1])};
        float2v dg = {exp2_(acc[2][2 * p]), exp2_(acc[2][2 * p + 1])};
        float2v do_ = {exp2_(acc[3][2 * p]), exp2_(acc[3][2 * p + 1])};
        di += 1.0f; df += 1.0f; dg += 1.0f; do_ += 1.0f;
        float2v m1 = di * df, m2 = do_ * dg;
        float2v P = m1 * m2;                       // di*df*do*dg
        float Rs = rcp_(P.x * P.y);                // one rcp for 8 factors
        float2v R = {Rs * P.y, Rs * P.x};
        float2v i_ = (df * m2) * R;                // = 1/di
        float2v f_ = (di * m2) * R;                // = 1/df
        float2v o_ = (m1 * dg) * R;                // = 1/do
        float2v g_ = 1.0f - 2.0f * ((m1 * do_) * R);  // = 1-2/dg
        float2v cn = f_ * cst[p] + i_ * g_;
        cst[p] = cn;
        float2v s = cn * (2.0f * LOG2E);
        float2v dc = {exp2_(s.x), exp2_(s.y)};
        dc += 1.0f;
        float Rc = rcp_(dc.x * dc.y);
        float2v tc = 1.0f - 2.0f * float2v{Rc * dc.y, Rc * dc.x};
        float2v h = o_ * tc;
        unsigned pk = cvt_pk_bf16(h.x, h.y);
        int a0 = cb0 + p * 16;
        bt[a0] = (u16)pk;
        bt[a0 + 8] = (u16)(pk >> 16);
      }
      __syncthreads();  // publish h^l_t for next step's recurrent read
    }
  }

  // ---- dense head: out = sigmoid(h^4_9 . (Wd1@Wd2) + beta) ----
  if (tid < MTILE) {
    int rr = tid;
    const u16* b9 = &buf[9 * 1024];
    float s = vdense[50];
    for (int k = 0; k < H_; ++k) {
      int kk = k >> 5, qd = (k & 31) >> 3, j = k & 7;
      s += bf2f(b9[kk * 512 + qd * 128 + rr * 8 + j]) * vdense[k];
    }
    out[b0 + tid] = sig_nat(s);
  }
}

extern "C" void kernel_launch(void* const* d_in, const int* in_sizes, int n_in,
                              void* d_out, int out_size, void* d_ws,
                              size_t ws_size, hipStream_t stream) {
  const float* x = (const float*)d_in[0];
  const float* W1 = (const float*)d_in[1];
  const float* U1 = (const float*)d_in[2];
  const float* b1 = (const float*)d_in[3];
  const float* W2 = (const float*)d_in[4];
  const float* U2 = (const float*)d_in[5];
  const float* b2 = (const float*)d_in[6];
  const float* W3 = (const float*)d_in[7];
  const float* U3 = (const float*)d_in[8];
  const float* b3 = (const float*)d_in[9];
  const float* W4 = (const float*)d_in[10];
  const float* U4 = (const float*)d_in[11];
  const float* b4 = (const float*)d_in[12];
  const float* Wd1 = (const float*)d_in[13];
  const float* bd1 = (const float*)d_in[14];
  const float* Wd2 = (const float*)d_in[15];
  const float* bd2 = (const float*)d_in[16];

  const int Bn = in_sizes[0] / (T_ * F_);  // 131072
  const int nblk = Bn / MTILE;             // 8192
  char* ws = (char*)d_ws;
  u16* Wpp = (u16*)ws;                          // 4 x 32768 bf16 = 256 KB
  float* biasP = (float*)(ws + 262144);         // 4 x 256 f32
  float* vdense = (float*)(ws + 262144 + 4096); // 51 f32
  float* out = (float*)d_out;

  prep_kernel<<<(4 * 32768 + 1024 + 51 + 255) / 256, 256, 0, stream>>>(
      W1, U1, b1, W2, U2, b2, W3, U3, b3, W4, U4, b4, Wd1, bd1, Wd2, bd2, Wpp,
      biasP, vdense);

  lstm_fused<<<dim3(nblk), dim3(BLKT), 0, stream>>>(x, Wpp, biasP, vdense, out);
}

// Round 5
// 500.565 us; speedup vs baseline: 1.0062x; 1.0062x over previous
//
#include <hip/hip_runtime.h>

// RNN_73813307949430: 4x LSTM(H=50,T=10,F=5) + Dense(50) + Dense(1,sigmoid), B=131072.
// Round 8: R7 + __launch_bounds__(256,4). Register model revision: rocprof VGPR_Count
// is ARCH-only; the 64-reg bfr weight block sits in AGPRs (unified file) so total was
// ~132 > 128 -> 3 waves/SIMD in R4-R7 regardless of LDS. R5 proved (,4) forces the
// total to 128 (occupancy jumped 41.6%) but MTILE=32's ~150-reg live set spilled.
// MTILE=16's live set is ~116 <= 128 -> expect 4 blocks/CU with NO spill
// (tripwire: WRITE_SIZE must stay ~512 KB).
//
// LDS buf per t (1024 u16 = 2 KB): chunk(kk,quad) at u16 offset (kk*4+quad)*128+rr*8
// holds h[row=rr][unit=kk*32+quad*8+j]. MFMA A-frag: lane(np,quad) reads 16B at
// t*1024 + kk*512 + quad*128 + np*8 -> consecutive per lane = conflict-free.
// Weights Wpp: k 0..63 = X/h^{l-1}, k 64..127 = recurrent, prescaled by +-log2e.
// 1 barrier/step: X comes from regs (prefetched from buf[t+1]/buf[0] last step),
// reads touch only buf[t-1] and buf[t+1], disjoint from gate writes to buf[t].

typedef __attribute__((ext_vector_type(8))) short short8;
typedef __attribute__((ext_vector_type(4))) float floatx4;
typedef __attribute__((ext_vector_type(2))) float float2v;
typedef unsigned short u16;
typedef unsigned int u32;

constexpr int H_ = 50, T_ = 10, F_ = 5;
constexpr int MTILE = 16;   // batch rows per block
constexpr int BLKT = 256;   // 4 waves
constexpr float LOG2E = 1.4426950408889634f;

__device__ __forceinline__ float rcp_(float x) { return __builtin_amdgcn_rcpf(x); }
__device__ __forceinline__ float exp2_(float x) { return __builtin_amdgcn_exp2f(x); }
__device__ __forceinline__ float sig_nat(float x) {
  return rcp_(1.0f + exp2_(-LOG2E * x));
}

__device__ __forceinline__ u16 f2bf(float f) {
  union { float f; unsigned u; } v; v.f = f;
  unsigned r = v.u + 0x7FFFu + ((v.u >> 16) & 1u);  // RNE
  return (u16)(r >> 16);
}
__device__ __forceinline__ float bf2f(u16 s) {
  union { unsigned u; float f; } v; v.u = ((unsigned)s) << 16;
  return v.f;
}
// gfx950 packed f32->bf16 RNE convert (no builtin; inline asm). lo->bits[15:0].
__device__ __forceinline__ unsigned cvt_pk_bf16(float lo, float hi) {
  unsigned r;
  asm("v_cvt_pk_bf16_f32 %0, %1, %2" : "=v"(r) : "v"(lo), "v"(hi));
  return r;
}

// ---- prep: swizzle weights into B-fragment order with activation prescale ----
// Wpp[layer][kt][gate][wave][lane][8]; B[k=(lane>>4)*8+j][n=lane&15].
// Gates i,f,o scaled by -log2e (sig = rcp(1+exp2(z))); gate g by +2*log2e
// (tanh = 1-2*rcp(1+exp2(z))). Bias scaled identically.
__global__ void prep_kernel(
    const float* W1, const float* U1, const float* b1, const float* W2,
    const float* U2, const float* b2, const float* W3, const float* U3,
    const float* b3, const float* W4, const float* U4, const float* b4,
    const float* Wd1, const float* bd1, const float* Wd2, const float* bd2,
    u16* Wpp, float* biasP, float* vdense) {
  int idx = blockIdx.x * blockDim.x + threadIdx.x;
  const float* Wt[4] = {W1, W2, W3, W4};
  const float* Ut[4] = {U1, U2, U3, U4};
  const float* bt[4] = {b1, b2, b3, b4};
  const int fin[4] = {F_, H_, H_, H_};
  if (idx < 4 * 32768) {
    int l = idx >> 15, r = idx & 32767;
    int j = r & 7, lane = (r >> 3) & 63, w = (r >> 9) & 3, gI = (r >> 11) & 3,
        kt = r >> 13;
    int row = kt * 32 + (lane >> 4) * 8 + j;  // K position (0..127)
    int u = w * 16 + (lane & 15);             // unit (0..63)
    float val = 0.0f;
    if (u < H_) {
      if (row < 64) {
        if (row < fin[l]) val = Wt[l][row * 200 + gI * H_ + u];
      } else {
        int rr = row - 64;
        if (rr < H_) val = Ut[l][rr * 200 + gI * H_ + u];
      }
    }
    val *= (gI == 2) ? (2.0f * LOG2E) : (-LOG2E);
    Wpp[idx] = f2bf(val);
  } else if (idx < 4 * 32768 + 1024) {
    int r = idx - 4 * 32768;
    int l = r >> 8, q = r & 255, gI = q >> 6, u = q & 63;
    float val = (u < H_) ? bt[l][gI * H_ + u] : 0.0f;
    biasP[r] = val * ((gI == 2) ? (2.0f * LOG2E) : (-LOG2E));
  } else if (idx < 4 * 32768 + 1024 + 51) {
    int u = idx - (4 * 32768 + 1024);
    if (u < H_) {  // v = Wd1 @ Wd2 (Dense(50) linear -> collapse)
      float s = 0.0f;
      for (int n = 0; n < H_; ++n) s += Wd1[u * H_ + n] * Wd2[n];
      vdense[u] = s;
    } else {
      float s = bd2[0];
      for (int n = 0; n < H_; ++n) s += bd1[n] * Wd2[n];
      vdense[50] = s;
    }
  }
}

// ---- fully fused 4-layer LSTM + dense head ----
__global__ __launch_bounds__(BLKT, 4) void lstm_fused(
    const float* __restrict__ x0, const u16* __restrict__ Wpp,
    const float* __restrict__ biasP, const float* __restrict__ vdense,
    float* __restrict__ out) {
  // buf[t]: 1024 u16 (2 KB). Holds x (layer 0 input) at k=0..4, then in-place
  // h^{l-1}_t as X input, overwritten with h^l_t in the gate phase.
  __shared__ __align__(16) u16 buf[T_ * 1024];  // 20480 B

  const int tid = threadIdx.x;
  const int w = tid >> 6, lane = tid & 63;
  const int np = lane & 15, quad = lane >> 4;
  const int b0 = blockIdx.x * MTILE;
  const int u = w * 16 + np;

  // zero-fill buf once (layer-0 kt=0 MFMA reads k=5..31 slots; weights there are
  // zero, but LDS garbage could be NaN -> 0*NaN=NaN, so they must be real zeros)
  for (int i = tid; i < T_ * 512; i += BLKT) ((u32*)buf)[i] = 0;
  __syncthreads();
  // stage ALL timesteps of layer-1 input into buf[t] fragment slots (k=f, 0..4)
  for (int e = tid; e < MTILE * 50; e += BLKT) {
    int row = e / 50, q = e - row * 50;
    int t = q / 5, f = q - t * 5;
    buf[t * 1024 + row * 8 + f] = f2bf(x0[(size_t)(b0 + row) * 50 + q]);
  }
  __syncthreads();

  // A-frag read base: chunk(kk,quad,rr=np) -> kk*512 + quad*128 + np*8
  const int rbase = quad * 128 + np * 8;
  // h-write base: unit u -> kk=u>>5=w>>1, qk=((w&1)*2+(np>>3)), j=np&7; rows quad*4+2p
  const int cb0 = (w >> 1) * 512 + ((w & 1) * 2 + (np >> 3)) * 128 + quad * 32 + (np & 7);

  float2v cst[2];  // c state pairs: [p], rows quad*4+{2p,2p+1}, unit u

  // X fragments for the CURRENT step, prefetched one step ahead.
  short8 xa0, xa1;
  xa0 = *(const short8*)&buf[rbase];  // l=0,t=0 prologue: x in buf[0], kt=0 only
  xa1 = xa0;                          // unused for l=0 (defined to avoid UB)

#pragma unroll 1
  for (int l = 0; l < 4; ++l) {
    // per-layer weight fragments from L2 (prescaled), 64 regs (AGPR-resident)
    const u16* wp = Wpp + l * 32768;
    short8 bfr[4][4];
#pragma unroll
    for (int kt = 0; kt < 4; ++kt)
#pragma unroll
      for (int g = 0; g < 4; ++g)
        bfr[kt][g] = *(const short8*)&wp[(((kt * 4 + g) * 4 + w) * 64 + lane) * 8];
    float bv[4];
#pragma unroll
    for (int g = 0; g < 4; ++g) bv[g] = biasP[l * 256 + g * 64 + u];
    cst[0] = float2v{0.0f, 0.0f};
    cst[1] = float2v{0.0f, 0.0f};

#pragma unroll 1
    for (int t = 0; t < T_; ++t) {
      u16* bt = &buf[t * 1024];
      const u16* bp = &buf[(t == 0 ? 0 : (t - 1)) * 1024];

      floatx4 acc[4];
#pragma unroll
      for (int g = 0; g < 4; ++g) acc[g] = floatx4{bv[g], bv[g], bv[g], bv[g]};

      // X = prefetched regs (x for l=0 -> kt=0 only; h^{l-1}_t for l>0).
#pragma unroll
      for (int g = 0; g < 4; ++g)
        acc[g] = __builtin_amdgcn_mfma_f32_16x16x32_bf16(xa0, bfr[0][g], acc[g],
                                                         0, 0, 0);
      if (l > 0) {
#pragma unroll
        for (int g = 0; g < 4; ++g)
          acc[g] = __builtin_amdgcn_mfma_f32_16x16x32_bf16(xa1, bfr[1][g],
                                                           acc[g], 0, 0, 0);
      }
      if (t > 0) {  // recurrent H = h^l_{t-1} in buf[t-1]; h_{-1}=0 -> skip at t=0
        short8 h0 = *(const short8*)&bp[rbase];
        short8 h1 = *(const short8*)&bp[512 + rbase];
#pragma unroll
        for (int g = 0; g < 4; ++g) {
          acc[g] = __builtin_amdgcn_mfma_f32_16x16x32_bf16(h0, bfr[2][g], acc[g],
                                                           0, 0, 0);
          acc[g] = __builtin_amdgcn_mfma_f32_16x16x32_bf16(h1, bfr[3][g], acc[g],
                                                           0, 0, 0);
        }
      }

      // ---- prefetch next step's X frags (in flight under the gate phase) ----
      // t<9: buf[t+1] (overwritten only at step t+1, after the barrier).
      // t==9, l<3: buf[0] = h^l_0 for next layer (final since step 0).
      if (t < T_ - 1) {
        const u16* ns = &buf[(t + 1) * 1024];
        xa0 = *(const short8*)&ns[rbase];
        if (l > 0) xa1 = *(const short8*)&ns[512 + rbase];
      } else if (l < 3) {
        xa0 = *(const short8*)&buf[rbase];
        xa1 = *(const short8*)&buf[512 + rbase];
      }

      // NO pre-gate barrier: this step's LDS reads touch only buf[t-1] and
      // buf[t+1]/buf[0], all disjoint from the gate writes to buf[t]. The X-reads
      // of buf[t] happened last step, before the end-of-step barrier.

      // ---- gates: pairwise (v_pk_f32), shared reciprocals, prescaled z ----
#pragma unroll
      for (int p = 0; p < 2; ++p) {
        float2v di = {exp2_(acc[0][2 * p]), exp2_(acc[0][2 * p + 1])};
        float2v df = {exp2_(acc[1][2 * p]), exp2_(acc[1][2 * p + 1])};
        float2v dg = {exp2_(acc[2][2 * p]), exp2_(acc[2][2 * p + 1])};
        float2v do_ = {exp2_(acc[3][2 * p]), exp2_(acc[3][2 * p + 1])};
        di += 1.0f; df += 1.0f; dg += 1.0f; do_ += 1.0f;
        float2v m1 = di * df, m2 = do_ * dg;
        float2v P = m1 * m2;                       // di*df*do*dg
        float Rs = rcp_(P.x * P.y);                // one rcp for 8 factors
        float2v R = {Rs * P.y, Rs * P.x};
        float2v i_ = (df * m2) * R;                // = 1/di
        float2v f_ = (di * m2) * R;                // = 1/df
        float2v o_ = (m1 * dg) * R;                // = 1/do
        float2v g_ = 1.0f - 2.0f * ((m1 * do_) * R);  // = 1-2/dg
        float2v cn = f_ * cst[p] + i_ * g_;
        cst[p] = cn;
        float2v s = cn * (2.0f * LOG2E);
        float2v dc = {exp2_(s.x), exp2_(s.y)};
        dc += 1.0f;
        float Rc = rcp_(dc.x * dc.y);
        float2v tc = 1.0f - 2.0f * float2v{Rc * dc.y, Rc * dc.x};
        float2v h = o_ * tc;
        unsigned pk = cvt_pk_bf16(h.x, h.y);
        int a0 = cb0 + p * 16;
        bt[a0] = (u16)pk;
        bt[a0 + 8] = (u16)(pk >> 16);
      }
      __syncthreads();  // publish h^l_t for next step's recurrent read
    }
  }

  // ---- dense head: out = sigmoid(h^4_9 . (Wd1@Wd2) + beta) ----
  if (tid < MTILE) {
    int rr = tid;
    const u16* b9 = &buf[9 * 1024];
    float s = vdense[50];
    for (int k = 0; k < H_; ++k) {
      int kk = k >> 5, qd = (k & 31) >> 3, j = k & 7;
      s += bf2f(b9[kk * 512 + qd * 128 + rr * 8 + j]) * vdense[k];
    }
    out[b0 + tid] = sig_nat(s);
  }
}

extern "C" void kernel_launch(void* const* d_in, const int* in_sizes, int n_in,
                              void* d_out, int out_size, void* d_ws,
                              size_t ws_size, hipStream_t stream) {
  const float* x = (const float*)d_in[0];
  const float* W1 = (const float*)d_in[1];
  const float* U1 = (const float*)d_in[2];
  const float* b1 = (const float*)d_in[3];
  const float* W2 = (const float*)d_in[4];
  const float* U2 = (const float*)d_in[5];
  const float* b2 = (const float*)d_in[6];
  const float* W3 = (const float*)d_in[7];
  const float* U3 = (const float*)d_in[8];
  const float* b3 = (const float*)d_in[9];
  const float* W4 = (const float*)d_in[10];
  const float* U4 = (const float*)d_in[11];
  const float* b4 = (const float*)d_in[12];
  const float* Wd1 = (const float*)d_in[13];
  const float* bd1 = (const float*)d_in[14];
  const float* Wd2 = (const float*)d_in[15];
  const float* bd2 = (const float*)d_in[16];

  const int Bn = in_sizes[0] / (T_ * F_);  // 131072
  const int nblk = Bn / MTILE;             // 8192
  char* ws = (char*)d_ws;
  u16* Wpp = (u16*)ws;                          // 4 x 32768 bf16 = 256 KB
  float* biasP = (float*)(ws + 262144);         // 4 x 256 f32
  float* vdense = (float*)(ws + 262144 + 4096); // 51 f32
  float* out = (float*)d_out;

  prep_kernel<<<(4 * 32768 + 1024 + 51 + 255) / 256, 256, 0, stream>>>(
      W1, U1, b1, W2, U2, b2, W3, U3, b3, W4, U4, b4, Wd1, bd1, Wd2, bd2, Wpp,
      biasP, vdense);

  lstm_fused<<<dim3(nblk), dim3(BLKT), 0, stream>>>(x, Wpp, biasP, vdense, out);
}

// Round 6
// 497.748 us; speedup vs baseline: 1.0119x; 1.0057x over previous
//
#include <hip/hip_runtime.h>

// RNN_73813307949430: 4x LSTM(H=50,T=10,F=5) + Dense(50) + Dense(1,sigmoid), B=131072.
// Round 9: layer-parity double buffer. buf[2][T][1024]: layer l reads X from
// buf[l&1][t], H from buf[(l&1)^1][t-1], writes buf[(l&1)^1][t] — reads and writes
// hit disjoint buffers every step, so the 1-barrier/step schedule needs NO prefetch
// registers and NO layer-transition branch (R8's spill source: xa regs pushed the
// live set past the 128-reg granule -> 12MB scratch). LDS 40960 B = 160KiB/4 exactly;
// live set ~115 fits the (256,4) cap -> 4 blocks/CU, zero spill (tripwire: WRITE_SIZE
// must stay ~512 KB).
//
// LDS buf half per t (1024 u16 = 2 KB): chunk(kk,quad) at u16 offset
// (kk*4+quad)*128+rr*8 holds h[row=rr][unit=kk*32+quad*8+j]. MFMA A-frag:
// lane(np,quad) reads 16B at kk*512+quad*128+np*8 -> conflict-free.
// Weights Wpp: k 0..63 = X/h^{l-1}, k 64..127 = recurrent, prescaled by +-log2e.

typedef __attribute__((ext_vector_type(8))) short short8;
typedef __attribute__((ext_vector_type(4))) float floatx4;
typedef __attribute__((ext_vector_type(2))) float float2v;
typedef unsigned short u16;
typedef unsigned int u32;

constexpr int H_ = 50, T_ = 10, F_ = 5;
constexpr int MTILE = 16;   // batch rows per block
constexpr int BLKT = 256;   // 4 waves
constexpr float LOG2E = 1.4426950408889634f;

__device__ __forceinline__ float rcp_(float x) { return __builtin_amdgcn_rcpf(x); }
__device__ __forceinline__ float exp2_(float x) { return __builtin_amdgcn_exp2f(x); }
__device__ __forceinline__ float sig_nat(float x) {
  return rcp_(1.0f + exp2_(-LOG2E * x));
}

__device__ __forceinline__ u16 f2bf(float f) {
  union { float f; unsigned u; } v; v.f = f;
  unsigned r = v.u + 0x7FFFu + ((v.u >> 16) & 1u);  // RNE
  return (u16)(r >> 16);
}
__device__ __forceinline__ float bf2f(u16 s) {
  union { unsigned u; float f; } v; v.u = ((unsigned)s) << 16;
  return v.f;
}
// gfx950 packed f32->bf16 RNE convert (no builtin; inline asm). lo->bits[15:0].
__device__ __forceinline__ unsigned cvt_pk_bf16(float lo, float hi) {
  unsigned r;
  asm("v_cvt_pk_bf16_f32 %0, %1, %2" : "=v"(r) : "v"(lo), "v"(hi));
  return r;
}

// ---- prep: swizzle weights into B-fragment order with activation prescale ----
// Wpp[layer][kt][gate][wave][lane][8]; B[k=(lane>>4)*8+j][n=lane&15].
// Gates i,f,o scaled by -log2e (sig = rcp(1+exp2(z))); gate g by +2*log2e
// (tanh = 1-2*rcp(1+exp2(z))). Bias scaled identically.
__global__ void prep_kernel(
    const float* W1, const float* U1, const float* b1, const float* W2,
    const float* U2, const float* b2, const float* W3, const float* U3,
    const float* b3, const float* W4, const float* U4, const float* b4,
    const float* Wd1, const float* bd1, const float* Wd2, const float* bd2,
    u16* Wpp, float* biasP, float* vdense) {
  int idx = blockIdx.x * blockDim.x + threadIdx.x;
  const float* Wt[4] = {W1, W2, W3, W4};
  const float* Ut[4] = {U1, U2, U3, U4};
  const float* bt[4] = {b1, b2, b3, b4};
  const int fin[4] = {F_, H_, H_, H_};
  if (idx < 4 * 32768) {
    int l = idx >> 15, r = idx & 32767;
    int j = r & 7, lane = (r >> 3) & 63, w = (r >> 9) & 3, gI = (r >> 11) & 3,
        kt = r >> 13;
    int row = kt * 32 + (lane >> 4) * 8 + j;  // K position (0..127)
    int u = w * 16 + (lane & 15);             // unit (0..63)
    float val = 0.0f;
    if (u < H_) {
      if (row < 64) {
        if (row < fin[l]) val = Wt[l][row * 200 + gI * H_ + u];
      } else {
        int rr = row - 64;
        if (rr < H_) val = Ut[l][rr * 200 + gI * H_ + u];
      }
    }
    val *= (gI == 2) ? (2.0f * LOG2E) : (-LOG2E);
    Wpp[idx] = f2bf(val);
  } else if (idx < 4 * 32768 + 1024) {
    int r = idx - 4 * 32768;
    int l = r >> 8, q = r & 255, gI = q >> 6, u = q & 63;
    float val = (u < H_) ? bt[l][gI * H_ + u] : 0.0f;
    biasP[r] = val * ((gI == 2) ? (2.0f * LOG2E) : (-LOG2E));
  } else if (idx < 4 * 32768 + 1024 + 51) {
    int u = idx - (4 * 32768 + 1024);
    if (u < H_) {  // v = Wd1 @ Wd2 (Dense(50) linear -> collapse)
      float s = 0.0f;
      for (int n = 0; n < H_; ++n) s += Wd1[u * H_ + n] * Wd2[n];
      vdense[u] = s;
    } else {
      float s = bd2[0];
      for (int n = 0; n < H_; ++n) s += bd1[n] * Wd2[n];
      vdense[50] = s;
    }
  }
}

// ---- fully fused 4-layer LSTM + dense head ----
__global__ __launch_bounds__(BLKT, 4) void lstm_fused(
    const float* __restrict__ x0, const u16* __restrict__ Wpp,
    const float* __restrict__ biasP, const float* __restrict__ vdense,
    float* __restrict__ out) {
  // Two parity buffers. buf[0] starts as x (layer-0 input); each layer writes its
  // h into the opposite-parity buffer: l0: 0->1, l1: 1->0, l2: 0->1, l3: 1->0.
  __shared__ __align__(16) u16 buf[2][T_ * 1024];  // 40960 B = 160KiB/4 exactly

  const int tid = threadIdx.x;
  const int w = tid >> 6, lane = tid & 63;
  const int np = lane & 15, quad = lane >> 4;
  const int b0 = blockIdx.x * MTILE;
  const int u = w * 16 + np;

  // zero-fill both buffers (pad k-slots and garbage-unit slots must be finite
  // zeros: zero weights * NaN = NaN would poison the MFMA)
  for (int i = tid; i < 2 * T_ * 512; i += BLKT) ((u32*)buf)[i] = 0;
  __syncthreads();
  // stage ALL timesteps of layer-1 input into buf[0][t] fragment slots (k=f, 0..4)
  for (int e = tid; e < MTILE * 50; e += BLKT) {
    int row = e / 50, q = e - row * 50;
    int t = q / 5, f = q - t * 5;
    buf[0][t * 1024 + row * 8 + f] = f2bf(x0[(size_t)(b0 + row) * 50 + q]);
  }
  __syncthreads();

  // A-frag read base: chunk(kk,quad,rr=np) -> kk*512 + quad*128 + np*8
  const int rbase = quad * 128 + np * 8;
  // h-write base: unit u -> kk=u>>5=w>>1, qk=((w&1)*2+(np>>3)), j=np&7; rows quad*4+2p
  const int cb0 = (w >> 1) * 512 + ((w & 1) * 2 + (np >> 3)) * 128 + quad * 32 + (np & 7);

  float2v cst[2];  // c state pairs: [p], rows quad*4+{2p,2p+1}, unit u

#pragma unroll 1
  for (int l = 0; l < 4; ++l) {
    // per-layer weight fragments from L2 (prescaled), 64 regs (AGPR-resident)
    const u16* wp = Wpp + l * 32768;
    short8 bfr[4][4];
#pragma unroll
    for (int kt = 0; kt < 4; ++kt)
#pragma unroll
      for (int g = 0; g < 4; ++g)
        bfr[kt][g] = *(const short8*)&wp[(((kt * 4 + g) * 4 + w) * 64 + lane) * 8];
    float bv[4];
#pragma unroll
    for (int g = 0; g < 4; ++g) bv[g] = biasP[l * 256 + g * 64 + u];
    cst[0] = float2v{0.0f, 0.0f};
    cst[1] = float2v{0.0f, 0.0f};

    const u16* bufX = buf[l & 1];        // X source: x (l=0) or h^{l-1}
    u16* bufW = buf[(l & 1) ^ 1];        // write target; also H source (own h)

#pragma unroll 1
    for (int t = 0; t < T_; ++t) {
      floatx4 acc[4];
#pragma unroll
      for (int g = 0; g < 4; ++g) acc[g] = floatx4{bv[g], bv[g], bv[g], bv[g]};

      // X-half MFMA (l=0: k=5..63 weights zero -> kt=0 only)
      const u16* bx = bufX + t * 1024;
      short8 a0 = *(const short8*)&bx[rbase];
#pragma unroll
      for (int g = 0; g < 4; ++g)
        acc[g] = __builtin_amdgcn_mfma_f32_16x16x32_bf16(a0, bfr[0][g], acc[g],
                                                         0, 0, 0);
      if (l > 0) {
        short8 a1 = *(const short8*)&bx[512 + rbase];
#pragma unroll
        for (int g = 0; g < 4; ++g)
          acc[g] = __builtin_amdgcn_mfma_f32_16x16x32_bf16(a1, bfr[1][g],
                                                           acc[g], 0, 0, 0);
      }
      if (t > 0) {  // recurrent H = own h_{t-1} in bufW[t-1]; h_{-1}=0 -> skip
        const u16* bp = bufW + (t - 1) * 1024;
        short8 h0 = *(const short8*)&bp[rbase];
        short8 h1 = *(const short8*)&bp[512 + rbase];
#pragma unroll
        for (int g = 0; g < 4; ++g) {
          acc[g] = __builtin_amdgcn_mfma_f32_16x16x32_bf16(h0, bfr[2][g], acc[g],
                                                           0, 0, 0);
          acc[g] = __builtin_amdgcn_mfma_f32_16x16x32_bf16(h1, bfr[3][g], acc[g],
                                                           0, 0, 0);
        }
      }

      // All reads this step touched bufX[t] and bufW[t-1]; writes go to bufW[t]
      // -> disjoint, no pre-gate barrier needed.

      // ---- gates: pairwise (v_pk_f32), shared reciprocals, prescaled z ----
      u16* bw = bufW + t * 1024;
#pragma unroll
      for (int p = 0; p < 2; ++p) {
        float2v di = {exp2_(acc[0][2 * p]), exp2_(acc[0][2 * p + 1])};
        float2v df = {exp2_(acc[1][2 * p]), exp2_(acc[1][2 * p + 1])};
        float2v dg = {exp2_(acc[2][2 * p]), exp2_(acc[2][2 * p + 1])};
        float2v do_ = {exp2_(acc[3][2 * p]), exp2_(acc[3][2 * p + 1])};
        di += 1.0f; df += 1.0f; dg += 1.0f; do_ += 1.0f;
        float2v m1 = di * df, m2 = do_ * dg;
        float2v P = m1 * m2;                       // di*df*do*dg
        float Rs = rcp_(P.x * P.y);                // one rcp for 8 factors
        float2v R = {Rs * P.y, Rs * P.x};
        float2v i_ = (df * m2) * R;                // = 1/di
        float2v f_ = (di * m2) * R;                // = 1/df
        float2v o_ = (m1 * dg) * R;                // = 1/do
        float2v g_ = 1.0f - 2.0f * ((m1 * do_) * R);  // = 1-2/dg
        float2v cn = f_ * cst[p] + i_ * g_;
        cst[p] = cn;
        float2v s = cn * (2.0f * LOG2E);
        float2v dc = {exp2_(s.x), exp2_(s.y)};
        dc += 1.0f;
        float Rc = rcp_(dc.x * dc.y);
        float2v tc = 1.0f - 2.0f * float2v{Rc * dc.y, Rc * dc.x};
        float2v h = o_ * tc;
        unsigned pk = cvt_pk_bf16(h.x, h.y);
        int a0w = cb0 + p * 16;
        bw[a0w] = (u16)pk;
        bw[a0w + 8] = (u16)(pk >> 16);
      }
      __syncthreads();  // publish h^l_t for next step's H read / next layer's X
    }
  }

  // ---- dense head: out = sigmoid(h^4_9 . (Wd1@Wd2) + beta) ----
  // layer 3 writes parity 0: h^4 lives in buf[0].
  if (tid < MTILE) {
    int rr = tid;
    const u16* b9 = &buf[0][9 * 1024];
    float s = vdense[50];
    for (int k = 0; k < H_; ++k) {
      int kk = k >> 5, qd = (k & 31) >> 3, j = k & 7;
      s += bf2f(b9[kk * 512 + qd * 128 + rr * 8 + j]) * vdense[k];
    }
    out[b0 + tid] = sig_nat(s);
  }
}

extern "C" void kernel_launch(void* const* d_in, const int* in_sizes, int n_in,
                              void* d_out, int out_size, void* d_ws,
                              size_t ws_size, hipStream_t stream) {
  const float* x = (const float*)d_in[0];
  const float* W1 = (const float*)d_in[1];
  const float* U1 = (const float*)d_in[2];
  const float* b1 = (const float*)d_in[3];
  const float* W2 = (const float*)d_in[4];
  const float* U2 = (const float*)d_in[5];
  const float* b2 = (const float*)d_in[6];
  const float* W3 = (const float*)d_in[7];
  const float* U3 = (const float*)d_in[8];
  const float* b3 = (const float*)d_in[9];
  const float* W4 = (const float*)d_in[10];
  const float* U4 = (const float*)d_in[11];
  const float* b4 = (const float*)d_in[12];
  const float* Wd1 = (const float*)d_in[13];
  const float* bd1 = (const float*)d_in[14];
  const float* Wd2 = (const float*)d_in[15];
  const float* bd2 = (const float*)d_in[16];

  const int Bn = in_sizes[0] / (T_ * F_);  // 131072
  const int nblk = Bn / MTILE;             // 8192
  char* ws = (char*)d_ws;
  u16* Wpp = (u16*)ws;                          // 4 x 32768 bf16 = 256 KB
  float* biasP = (float*)(ws + 262144);         // 4 x 256 f32
  float* vdense = (float*)(ws + 262144 + 4096); // 51 f32
  float* out = (float*)d_out;

  prep_kernel<<<(4 * 32768 + 1024 + 51 + 255) / 256, 256, 0, stream>>>(
      W1, U1, b1, W2, U2, b2, W3, U3, b3, W4, U4, b4, Wd1, bd1, Wd2, bd2, Wpp,
      biasP, vdense);

  lstm_fused<<<dim3(nblk), dim3(BLKT), 0, stream>>>(x, Wpp, biasP, vdense, out);
}

// Round 7
// 478.614 us; speedup vs baseline: 1.0524x; 1.0400x over previous
//
#include <hip/hip_runtime.h>

// RNN_73813307949430: 4x LSTM(H=50,T=10,F=5) + Dense(50) + Dense(1,sigmoid), B=131072.
// Round 10: instruction-count cuts on R9's 448us structure (issue-port-bound:
// VALU 71% + MFMA 31%, occupancy 44%, spill ~0).
// (a) bias-as-MFMA-C: bias fragment bias4[g] built once per layer, used as the C
//     operand of each gate's first MFMA (D!=C) -> deletes 16 v_mov acc-inits/step.
// (b) plain-rcp gates: sig=rcp(1+exp2(z')), tanh=1-2*rcp(1+exp2(z')) per gate —
//     same trans-pipe cost as the shared-rcp trick, ~20 fewer issue slots/step.
// Structure unchanged: layer-parity double buffer buf[2][T][1024], 1 barrier/step,
// MTILE=16, 4 waves, launch_bounds(256,4), LDS 40960 B.
//
// LDS buf half per t (1024 u16 = 2 KB): chunk(kk,quad) at u16 offset
// (kk*4+quad)*128+rr*8 holds h[row=rr][unit=kk*32+quad*8+j]. MFMA A-frag:
// lane(np,quad) reads 16B at kk*512+quad*128+np*8 -> conflict-free.
// Weights Wpp: k 0..63 = X/h^{l-1}, k 64..127 = recurrent, prescaled by +-log2e.

typedef __attribute__((ext_vector_type(8))) short short8;
typedef __attribute__((ext_vector_type(4))) float floatx4;
typedef __attribute__((ext_vector_type(2))) float float2v;
typedef unsigned short u16;
typedef unsigned int u32;

constexpr int H_ = 50, T_ = 10, F_ = 5;
constexpr int MTILE = 16;   // batch rows per block
constexpr int BLKT = 256;   // 4 waves
constexpr float LOG2E = 1.4426950408889634f;

__device__ __forceinline__ float rcp_(float x) { return __builtin_amdgcn_rcpf(x); }
__device__ __forceinline__ float exp2_(float x) { return __builtin_amdgcn_exp2f(x); }
__device__ __forceinline__ float sig_nat(float x) {
  return rcp_(1.0f + exp2_(-LOG2E * x));
}

__device__ __forceinline__ u16 f2bf(float f) {
  union { float f; unsigned u; } v; v.f = f;
  unsigned r = v.u + 0x7FFFu + ((v.u >> 16) & 1u);  // RNE
  return (u16)(r >> 16);
}
__device__ __forceinline__ float bf2f(u16 s) {
  union { unsigned u; float f; } v; v.u = ((unsigned)s) << 16;
  return v.f;
}
// gfx950 packed f32->bf16 RNE convert (no builtin; inline asm). lo->bits[15:0].
__device__ __forceinline__ unsigned cvt_pk_bf16(float lo, float hi) {
  unsigned r;
  asm("v_cvt_pk_bf16_f32 %0, %1, %2" : "=v"(r) : "v"(lo), "v"(hi));
  return r;
}

// ---- prep: swizzle weights into B-fragment order with activation prescale ----
// Wpp[layer][kt][gate][wave][lane][8]; B[k=(lane>>4)*8+j][n=lane&15].
// Gates i,f,o scaled by -log2e (sig = rcp(1+exp2(z))); gate g by +2*log2e
// (tanh = 1-2*rcp(1+exp2(z))). Bias scaled identically.
__global__ void prep_kernel(
    const float* W1, const float* U1, const float* b1, const float* W2,
    const float* U2, const float* b2, const float* W3, const float* U3,
    const float* b3, const float* W4, const float* U4, const float* b4,
    const float* Wd1, const float* bd1, const float* Wd2, const float* bd2,
    u16* Wpp, float* biasP, float* vdense) {
  int idx = blockIdx.x * blockDim.x + threadIdx.x;
  const float* Wt[4] = {W1, W2, W3, W4};
  const float* Ut[4] = {U1, U2, U3, U4};
  const float* bt[4] = {b1, b2, b3, b4};
  const int fin[4] = {F_, H_, H_, H_};
  if (idx < 4 * 32768) {
    int l = idx >> 15, r = idx & 32767;
    int j = r & 7, lane = (r >> 3) & 63, w = (r >> 9) & 3, gI = (r >> 11) & 3,
        kt = r >> 13;
    int row = kt * 32 + (lane >> 4) * 8 + j;  // K position (0..127)
    int u = w * 16 + (lane & 15);             // unit (0..63)
    float val = 0.0f;
    if (u < H_) {
      if (row < 64) {
        if (row < fin[l]) val = Wt[l][row * 200 + gI * H_ + u];
      } else {
        int rr = row - 64;
        if (rr < H_) val = Ut[l][rr * 200 + gI * H_ + u];
      }
    }
    val *= (gI == 2) ? (2.0f * LOG2E) : (-LOG2E);
    Wpp[idx] = f2bf(val);
  } else if (idx < 4 * 32768 + 1024) {
    int r = idx - 4 * 32768;
    int l = r >> 8, q = r & 255, gI = q >> 6, u = q & 63;
    float val = (u < H_) ? bt[l][gI * H_ + u] : 0.0f;
    biasP[r] = val * ((gI == 2) ? (2.0f * LOG2E) : (-LOG2E));
  } else if (idx < 4 * 32768 + 1024 + 51) {
    int u = idx - (4 * 32768 + 1024);
    if (u < H_) {  // v = Wd1 @ Wd2 (Dense(50) linear -> collapse)
      float s = 0.0f;
      for (int n = 0; n < H_; ++n) s += Wd1[u * H_ + n] * Wd2[n];
      vdense[u] = s;
    } else {
      float s = bd2[0];
      for (int n = 0; n < H_; ++n) s += bd1[n] * Wd2[n];
      vdense[50] = s;
    }
  }
}

// ---- fully fused 4-layer LSTM + dense head ----
__global__ __launch_bounds__(BLKT, 4) void lstm_fused(
    const float* __restrict__ x0, const u16* __restrict__ Wpp,
    const float* __restrict__ biasP, const float* __restrict__ vdense,
    float* __restrict__ out) {
  // Two parity buffers. buf[0] starts as x (layer-0 input); each layer writes its
  // h into the opposite-parity buffer: l0: 0->1, l1: 1->0, l2: 0->1, l3: 1->0.
  __shared__ __align__(16) u16 buf[2][T_ * 1024];  // 40960 B = 160KiB/4 exactly

  const int tid = threadIdx.x;
  const int w = tid >> 6, lane = tid & 63;
  const int np = lane & 15, quad = lane >> 4;
  const int b0 = blockIdx.x * MTILE;
  const int u = w * 16 + np;

  // zero-fill both buffers (pad k-slots and garbage-unit slots must be finite
  // zeros: zero weights * NaN = NaN would poison the MFMA)
  for (int i = tid; i < 2 * T_ * 512; i += BLKT) ((u32*)buf)[i] = 0;
  __syncthreads();
  // stage ALL timesteps of layer-1 input into buf[0][t] fragment slots (k=f, 0..4)
  for (int e = tid; e < MTILE * 50; e += BLKT) {
    int row = e / 50, q = e - row * 50;
    int t = q / 5, f = q - t * 5;
    buf[0][t * 1024 + row * 8 + f] = f2bf(x0[(size_t)(b0 + row) * 50 + q]);
  }
  __syncthreads();

  // A-frag read base: chunk(kk,quad,rr=np) -> kk*512 + quad*128 + np*8
  const int rbase = quad * 128 + np * 8;
  // h-write base: unit u -> kk=u>>5=w>>1, qk=((w&1)*2+(np>>3)), j=np&7; rows quad*4+2p
  const int cb0 = (w >> 1) * 512 + ((w & 1) * 2 + (np >> 3)) * 128 + quad * 32 + (np & 7);

  float2v cst[2];  // c state pairs: [p], rows quad*4+{2p,2p+1}, unit u

#pragma unroll 1
  for (int l = 0; l < 4; ++l) {
    // per-layer weight fragments from L2 (prescaled), 64 regs (AGPR-resident)
    const u16* wp = Wpp + l * 32768;
    short8 bfr[4][4];
#pragma unroll
    for (int kt = 0; kt < 4; ++kt)
#pragma unroll
      for (int g = 0; g < 4; ++g)
        bfr[kt][g] = *(const short8*)&wp[(((kt * 4 + g) * 4 + w) * 64 + lane) * 8];
    // bias fragments: built once per layer, used as the C operand of each gate's
    // first MFMA every step (D != C, so bias4 is never clobbered).
    floatx4 bias4[4];
#pragma unroll
    for (int g = 0; g < 4; ++g) {
      float bv = biasP[l * 256 + g * 64 + u];
      bias4[g] = floatx4{bv, bv, bv, bv};
    }
    cst[0] = float2v{0.0f, 0.0f};
    cst[1] = float2v{0.0f, 0.0f};

    const u16* bufX = buf[l & 1];        // X source: x (l=0) or h^{l-1}
    u16* bufW = buf[(l & 1) ^ 1];        // write target; also H source (own h)

#pragma unroll 1
    for (int t = 0; t < T_; ++t) {
      floatx4 acc[4];

      // X-half MFMA (l=0: k=5..63 weights zero -> kt=0 only). First MFMA per
      // gate consumes bias4[g] as C — no acc init movs.
      const u16* bx = bufX + t * 1024;
      short8 a0 = *(const short8*)&bx[rbase];
#pragma unroll
      for (int g = 0; g < 4; ++g)
        acc[g] = __builtin_amdgcn_mfma_f32_16x16x32_bf16(a0, bfr[0][g],
                                                         bias4[g], 0, 0, 0);
      if (l > 0) {
        short8 a1 = *(const short8*)&bx[512 + rbase];
#pragma unroll
        for (int g = 0; g < 4; ++g)
          acc[g] = __builtin_amdgcn_mfma_f32_16x16x32_bf16(a1, bfr[1][g],
                                                           acc[g], 0, 0, 0);
      }
      if (t > 0) {  // recurrent H = own h_{t-1} in bufW[t-1]; h_{-1}=0 -> skip
        const u16* bp = bufW + (t - 1) * 1024;
        short8 h0 = *(const short8*)&bp[rbase];
        short8 h1 = *(const short8*)&bp[512 + rbase];
#pragma unroll
        for (int g = 0; g < 4; ++g) {
          acc[g] = __builtin_amdgcn_mfma_f32_16x16x32_bf16(h0, bfr[2][g], acc[g],
                                                           0, 0, 0);
          acc[g] = __builtin_amdgcn_mfma_f32_16x16x32_bf16(h1, bfr[3][g], acc[g],
                                                           0, 0, 0);
        }
      }

      // All reads this step touched bufX[t] and bufW[t-1]; writes go to bufW[t]
      // -> disjoint, no pre-gate barrier needed.

      // ---- gates: plain-rcp form (prescaled z: i,f,o by -log2e; g by 2log2e) ----
      u16* bw = bufW + t * 1024;
#pragma unroll
      for (int p = 0; p < 2; ++p) {
        float2v di = {exp2_(acc[0][2 * p]), exp2_(acc[0][2 * p + 1])};
        float2v df = {exp2_(acc[1][2 * p]), exp2_(acc[1][2 * p + 1])};
        float2v dg = {exp2_(acc[2][2 * p]), exp2_(acc[2][2 * p + 1])};
        float2v do_ = {exp2_(acc[3][2 * p]), exp2_(acc[3][2 * p + 1])};
        di += 1.0f; df += 1.0f; dg += 1.0f; do_ += 1.0f;
        float2v i_ = {rcp_(di.x), rcp_(di.y)};      // sigmoid(zi)
        float2v f_ = {rcp_(df.x), rcp_(df.y)};      // sigmoid(zf)
        float2v o_ = {rcp_(do_.x), rcp_(do_.y)};    // sigmoid(zo)
        float2v rg = {rcp_(dg.x), rcp_(dg.y)};
        float2v g_ = 1.0f - 2.0f * rg;              // tanh(zg)
        float2v cn = f_ * cst[p] + i_ * g_;
        cst[p] = cn;
        float2v s = cn * (2.0f * LOG2E);
        float2v dc = {exp2_(s.x), exp2_(s.y)};
        dc += 1.0f;
        float2v rc = {rcp_(dc.x), rcp_(dc.y)};
        float2v tc = 1.0f - 2.0f * rc;              // tanh(cn)
        float2v h = o_ * tc;
        unsigned pk = cvt_pk_bf16(h.x, h.y);
        int a0w = cb0 + p * 16;
        bw[a0w] = (u16)pk;
        bw[a0w + 8] = (u16)(pk >> 16);
      }
      __syncthreads();  // publish h^l_t for next step's H read / next layer's X
    }
  }

  // ---- dense head: out = sigmoid(h^4_9 . (Wd1@Wd2) + beta) ----
  // layer 3 writes parity 0: h^4 lives in buf[0].
  if (tid < MTILE) {
    int rr = tid;
    const u16* b9 = &buf[0][9 * 1024];
    float s = vdense[50];
    for (int k = 0; k < H_; ++k) {
      int kk = k >> 5, qd = (k & 31) >> 3, j = k & 7;
      s += bf2f(b9[kk * 512 + qd * 128 + rr * 8 + j]) * vdense[k];
    }
    out[b0 + tid] = sig_nat(s);
  }
}

extern "C" void kernel_launch(void* const* d_in, const int* in_sizes, int n_in,
                              void* d_out, int out_size, void* d_ws,
                              size_t ws_size, hipStream_t stream) {
  const float* x = (const float*)d_in[0];
  const float* W1 = (const float*)d_in[1];
  const float* U1 = (const float*)d_in[2];
  const float* b1 = (const float*)d_in[3];
  const float* W2 = (const float*)d_in[4];
  const float* U2 = (const float*)d_in[5];
  const float* b2 = (const float*)d_in[6];
  const float* W3 = (const float*)d_in[7];
  const float* U3 = (const float*)d_in[8];
  const float* b3 = (const float*)d_in[9];
  const float* W4 = (const float*)d_in[10];
  const float* U4 = (const float*)d_in[11];
  const float* b4 = (const float*)d_in[12];
  const float* Wd1 = (const float*)d_in[13];
  const float* bd1 = (const float*)d_in[14];
  const float* Wd2 = (const float*)d_in[15];
  const float* bd2 = (const float*)d_in[16];

  const int Bn = in_sizes[0] / (T_ * F_);  // 131072
  const int nblk = Bn / MTILE;             // 8192
  char* ws = (char*)d_ws;
  u16* Wpp = (u16*)ws;                          // 4 x 32768 bf16 = 256 KB
  float* biasP = (float*)(ws + 262144);         // 4 x 256 f32
  float* vdense = (float*)(ws + 262144 + 4096); // 51 f32
  float* out = (float*)d_out;

  prep_kernel<<<(4 * 32768 + 1024 + 51 + 255) / 256, 256, 0, stream>>>(
      W1, U1, b1, W2, U2, b2, W3, U3, b3, W4, U4, b4, Wd1, bd1, Wd2, bd2, Wpp,
      biasP, vdense);

  lstm_fused<<<dim3(nblk), dim3(BLKT), 0, stream>>>(x, Wpp, biasP, vdense, out);
}

// Round 8
// 474.656 us; speedup vs baseline: 1.0611x; 1.0083x over previous
//
#include <hip/hip_runtime.h>

// RNN_73813307949430: 4x LSTM(H=50,T=10,F=5) + Dense(50) + Dense(1,sigmoid), B=131072.
// Round 11: recombine R10(a) bias-as-MFMA-C with R9's shared-reciprocal gate math.
// R10's plain-rcp swap was mis-modeled: trans ops occupy the wave64 issue port ~8cy
// vs 2cy for packed VALU, so 8 rcp (64cy) >> 1 rcp + 13 pk ops (~34cy). Restoring
// shared-rcp cuts trans/step 40->26 (~-60 net issue-cycles of ~410). tanh(c) keeps
// plain rcp (2 values, short dep chain). Everything else = R10: layer-parity double
// buffer, 1 barrier/step, MTILE=16, 4 waves, launch_bounds(256,4), LDS 40960 B.
//
// LDS buf half per t (1024 u16 = 2 KB): chunk(kk,quad) at u16 offset
// (kk*4+quad)*128+rr*8 holds h[row=rr][unit=kk*32+quad*8+j]. MFMA A-frag:
// lane(np,quad) reads 16B at kk*512+quad*128+np*8 -> conflict-free.
// Weights Wpp: k 0..63 = X/h^{l-1}, k 64..127 = recurrent, prescaled by +-log2e.

typedef __attribute__((ext_vector_type(8))) short short8;
typedef __attribute__((ext_vector_type(4))) float floatx4;
typedef __attribute__((ext_vector_type(2))) float float2v;
typedef unsigned short u16;
typedef unsigned int u32;

constexpr int H_ = 50, T_ = 10, F_ = 5;
constexpr int MTILE = 16;   // batch rows per block
constexpr int BLKT = 256;   // 4 waves
constexpr float LOG2E = 1.4426950408889634f;

__device__ __forceinline__ float rcp_(float x) { return __builtin_amdgcn_rcpf(x); }
__device__ __forceinline__ float exp2_(float x) { return __builtin_amdgcn_exp2f(x); }
__device__ __forceinline__ float sig_nat(float x) {
  return rcp_(1.0f + exp2_(-LOG2E * x));
}

__device__ __forceinline__ u16 f2bf(float f) {
  union { float f; unsigned u; } v; v.f = f;
  unsigned r = v.u + 0x7FFFu + ((v.u >> 16) & 1u);  // RNE
  return (u16)(r >> 16);
}
__device__ __forceinline__ float bf2f(u16 s) {
  union { unsigned u; float f; } v; v.u = ((unsigned)s) << 16;
  return v.f;
}
// gfx950 packed f32->bf16 RNE convert (no builtin; inline asm). lo->bits[15:0].
__device__ __forceinline__ unsigned cvt_pk_bf16(float lo, float hi) {
  unsigned r;
  asm("v_cvt_pk_bf16_f32 %0, %1, %2" : "=v"(r) : "v"(lo), "v"(hi));
  return r;
}

// ---- prep: swizzle weights into B-fragment order with activation prescale ----
// Wpp[layer][kt][gate][wave][lane][8]; B[k=(lane>>4)*8+j][n=lane&15].
// Gates i,f,o scaled by -log2e (sig = rcp(1+exp2(z))); gate g by +2*log2e
// (tanh = 1-2*rcp(1+exp2(z))). Bias scaled identically.
__global__ void prep_kernel(
    const float* W1, const float* U1, const float* b1, const float* W2,
    const float* U2, const float* b2, const float* W3, const float* U3,
    const float* b3, const float* W4, const float* U4, const float* b4,
    const float* Wd1, const float* bd1, const float* Wd2, const float* bd2,
    u16* Wpp, float* biasP, float* vdense) {
  int idx = blockIdx.x * blockDim.x + threadIdx.x;
  const float* Wt[4] = {W1, W2, W3, W4};
  const float* Ut[4] = {U1, U2, U3, U4};
  const float* bt[4] = {b1, b2, b3, b4};
  const int fin[4] = {F_, H_, H_, H_};
  if (idx < 4 * 32768) {
    int l = idx >> 15, r = idx & 32767;
    int j = r & 7, lane = (r >> 3) & 63, w = (r >> 9) & 3, gI = (r >> 11) & 3,
        kt = r >> 13;
    int row = kt * 32 + (lane >> 4) * 8 + j;  // K position (0..127)
    int u = w * 16 + (lane & 15);             // unit (0..63)
    float val = 0.0f;
    if (u < H_) {
      if (row < 64) {
        if (row < fin[l]) val = Wt[l][row * 200 + gI * H_ + u];
      } else {
        int rr = row - 64;
        if (rr < H_) val = Ut[l][rr * 200 + gI * H_ + u];
      }
    }
    val *= (gI == 2) ? (2.0f * LOG2E) : (-LOG2E);
    Wpp[idx] = f2bf(val);
  } else if (idx < 4 * 32768 + 1024) {
    int r = idx - 4 * 32768;
    int l = r >> 8, q = r & 255, gI = q >> 6, u = q & 63;
    float val = (u < H_) ? bt[l][gI * H_ + u] : 0.0f;
    biasP[r] = val * ((gI == 2) ? (2.0f * LOG2E) : (-LOG2E));
  } else if (idx < 4 * 32768 + 1024 + 51) {
    int u = idx - (4 * 32768 + 1024);
    if (u < H_) {  // v = Wd1 @ Wd2 (Dense(50) linear -> collapse)
      float s = 0.0f;
      for (int n = 0; n < H_; ++n) s += Wd1[u * H_ + n] * Wd2[n];
      vdense[u] = s;
    } else {
      float s = bd2[0];
      for (int n = 0; n < H_; ++n) s += bd1[n] * Wd2[n];
      vdense[50] = s;
    }
  }
}

// ---- fully fused 4-layer LSTM + dense head ----
__global__ __launch_bounds__(BLKT, 4) void lstm_fused(
    const float* __restrict__ x0, const u16* __restrict__ Wpp,
    const float* __restrict__ biasP, const float* __restrict__ vdense,
    float* __restrict__ out) {
  // Two parity buffers. buf[0] starts as x (layer-0 input); each layer writes its
  // h into the opposite-parity buffer: l0: 0->1, l1: 1->0, l2: 0->1, l3: 1->0.
  __shared__ __align__(16) u16 buf[2][T_ * 1024];  // 40960 B = 160KiB/4 exactly

  const int tid = threadIdx.x;
  const int w = tid >> 6, lane = tid & 63;
  const int np = lane & 15, quad = lane >> 4;
  const int b0 = blockIdx.x * MTILE;
  const int u = w * 16 + np;

  // zero-fill both buffers (pad k-slots and garbage-unit slots must be finite
  // zeros: zero weights * NaN = NaN would poison the MFMA)
  for (int i = tid; i < 2 * T_ * 512; i += BLKT) ((u32*)buf)[i] = 0;
  __syncthreads();
  // stage ALL timesteps of layer-1 input into buf[0][t] fragment slots (k=f, 0..4)
  for (int e = tid; e < MTILE * 50; e += BLKT) {
    int row = e / 50, q = e - row * 50;
    int t = q / 5, f = q - t * 5;
    buf[0][t * 1024 + row * 8 + f] = f2bf(x0[(size_t)(b0 + row) * 50 + q]);
  }
  __syncthreads();

  // A-frag read base: chunk(kk,quad,rr=np) -> kk*512 + quad*128 + np*8
  const int rbase = quad * 128 + np * 8;
  // h-write base: unit u -> kk=u>>5=w>>1, qk=((w&1)*2+(np>>3)), j=np&7; rows quad*4+2p
  const int cb0 = (w >> 1) * 512 + ((w & 1) * 2 + (np >> 3)) * 128 + quad * 32 + (np & 7);

  float2v cst[2];  // c state pairs: [p], rows quad*4+{2p,2p+1}, unit u

#pragma unroll 1
  for (int l = 0; l < 4; ++l) {
    // per-layer weight fragments from L2 (prescaled), 64 regs (AGPR-resident)
    const u16* wp = Wpp + l * 32768;
    short8 bfr[4][4];
#pragma unroll
    for (int kt = 0; kt < 4; ++kt)
#pragma unroll
      for (int g = 0; g < 4; ++g)
        bfr[kt][g] = *(const short8*)&wp[(((kt * 4 + g) * 4 + w) * 64 + lane) * 8];
    // bias fragments: built once per layer, used as the C operand of each gate's
    // first MFMA every step (D != C, so bias4 is never clobbered).
    floatx4 bias4[4];
#pragma unroll
    for (int g = 0; g < 4; ++g) {
      float bv = biasP[l * 256 + g * 64 + u];
      bias4[g] = floatx4{bv, bv, bv, bv};
    }
    cst[0] = float2v{0.0f, 0.0f};
    cst[1] = float2v{0.0f, 0.0f};

    const u16* bufX = buf[l & 1];        // X source: x (l=0) or h^{l-1}
    u16* bufW = buf[(l & 1) ^ 1];        // write target; also H source (own h)

#pragma unroll 1
    for (int t = 0; t < T_; ++t) {
      floatx4 acc[4];

      // X-half MFMA (l=0: k=5..63 weights zero -> kt=0 only). First MFMA per
      // gate consumes bias4[g] as C — no acc init movs.
      const u16* bx = bufX + t * 1024;
      short8 a0 = *(const short8*)&bx[rbase];
#pragma unroll
      for (int g = 0; g < 4; ++g)
        acc[g] = __builtin_amdgcn_mfma_f32_16x16x32_bf16(a0, bfr[0][g],
                                                         bias4[g], 0, 0, 0);
      if (l > 0) {
        short8 a1 = *(const short8*)&bx[512 + rbase];
#pragma unroll
        for (int g = 0; g < 4; ++g)
          acc[g] = __builtin_amdgcn_mfma_f32_16x16x32_bf16(a1, bfr[1][g],
                                                           acc[g], 0, 0, 0);
      }
      if (t > 0) {  // recurrent H = own h_{t-1} in bufW[t-1]; h_{-1}=0 -> skip
        const u16* bp = bufW + (t - 1) * 1024;
        short8 h0 = *(const short8*)&bp[rbase];
        short8 h1 = *(const short8*)&bp[512 + rbase];
#pragma unroll
        for (int g = 0; g < 4; ++g) {
          acc[g] = __builtin_amdgcn_mfma_f32_16x16x32_bf16(h0, bfr[2][g], acc[g],
                                                           0, 0, 0);
          acc[g] = __builtin_amdgcn_mfma_f32_16x16x32_bf16(h1, bfr[3][g], acc[g],
                                                           0, 0, 0);
        }
      }

      // All reads this step touched bufX[t] and bufW[t-1]; writes go to bufW[t]
      // -> disjoint, no pre-gate barrier needed.

      // ---- gates: shared-rcp (1 trans for 8 gate factors), prescaled z ----
      u16* bw = bufW + t * 1024;
#pragma unroll
      for (int p = 0; p < 2; ++p) {
        float2v di = {exp2_(acc[0][2 * p]), exp2_(acc[0][2 * p + 1])};
        float2v df = {exp2_(acc[1][2 * p]), exp2_(acc[1][2 * p + 1])};
        float2v dg = {exp2_(acc[2][2 * p]), exp2_(acc[2][2 * p + 1])};
        float2v do_ = {exp2_(acc[3][2 * p]), exp2_(acc[3][2 * p + 1])};
        di += 1.0f; df += 1.0f; dg += 1.0f; do_ += 1.0f;
        float2v m1 = di * df, m2 = do_ * dg;
        float2v P = m1 * m2;                          // di*df*do*dg
        float Rs = rcp_(P.x * P.y);                   // one rcp for 8 factors
        float2v R = {Rs * P.y, Rs * P.x};             // = 1/P componentwise
        float2v i_ = (df * m2) * R;                   // = 1/di = sigmoid(zi)
        float2v f_ = (di * m2) * R;                   // = 1/df = sigmoid(zf)
        float2v o_ = (m1 * dg) * R;                   // = 1/do = sigmoid(zo)
        float2v g_ = 1.0f - 2.0f * ((m1 * do_) * R);  // = 1-2/dg = tanh(zg)
        float2v cn = f_ * cst[p] + i_ * g_;
        cst[p] = cn;
        float2v s = cn * (2.0f * LOG2E);
        float2v dc = {exp2_(s.x), exp2_(s.y)};
        dc += 1.0f;
        float2v rc = {rcp_(dc.x), rcp_(dc.y)};        // plain: short dep chain
        float2v tc = 1.0f - 2.0f * rc;                // tanh(cn)
        float2v h = o_ * tc;
        unsigned pk = cvt_pk_bf16(h.x, h.y);
        int a0w = cb0 + p * 16;
        bw[a0w] = (u16)pk;
        bw[a0w + 8] = (u16)(pk >> 16);
      }
      __syncthreads();  // publish h^l_t for next step's H read / next layer's X
    }
  }

  // ---- dense head: out = sigmoid(h^4_9 . (Wd1@Wd2) + beta) ----
  // layer 3 writes parity 0: h^4 lives in buf[0].
  if (tid < MTILE) {
    int rr = tid;
    const u16* b9 = &buf[0][9 * 1024];
    float s = vdense[50];
    for (int k = 0; k < H_; ++k) {
      int kk = k >> 5, qd = (k & 31) >> 3, j = k & 7;
      s += bf2f(b9[kk * 512 + qd * 128 + rr * 8 + j]) * vdense[k];
    }
    out[b0 + tid] = sig_nat(s);
  }
}

extern "C" void kernel_launch(void* const* d_in, const int* in_sizes, int n_in,
                              void* d_out, int out_size, void* d_ws,
                              size_t ws_size, hipStream_t stream) {
  const float* x = (const float*)d_in[0];
  const float* W1 = (const float*)d_in[1];
  const float* U1 = (const float*)d_in[2];
  const float* b1 = (const float*)d_in[3];
  const float* W2 = (const float*)d_in[4];
  const float* U2 = (const float*)d_in[5];
  const float* b2 = (const float*)d_in[6];
  const float* W3 = (const float*)d_in[7];
  const float* U3 = (const float*)d_in[8];
  const float* b3 = (const float*)d_in[9];
  const float* W4 = (const float*)d_in[10];
  const float* U4 = (const float*)d_in[11];
  const float* b4 = (const float*)d_in[12];
  const float* Wd1 = (const float*)d_in[13];
  const float* bd1 = (const float*)d_in[14];
  const float* Wd2 = (const float*)d_in[15];
  const float* bd2 = (const float*)d_in[16];

  const int Bn = in_sizes[0] / (T_ * F_);  // 131072
  const int nblk = Bn / MTILE;             // 8192
  char* ws = (char*)d_ws;
  u16* Wpp = (u16*)ws;                          // 4 x 32768 bf16 = 256 KB
  float* biasP = (float*)(ws + 262144);         // 4 x 256 f32
  float* vdense = (float*)(ws + 262144 + 4096); // 51 f32
  float* out = (float*)d_out;

  prep_kernel<<<(4 * 32768 + 1024 + 51 + 255) / 256, 256, 0, stream>>>(
      W1, U1, b1, W2, U2, b2, W3, U3, b3, W4, U4, b4, Wd1, bd1, Wd2, bd2, Wpp,
      biasP, vdense);

  lstm_fused<<<dim3(nblk), dim3(BLKT), 0, stream>>>(x, Wpp, biasP, vdense, out);
}